// Round 6
// baseline (107.971 us; speedup 1.0000x reference)
//
#include <hip/hip_runtime.h>
#include <hip/hip_bf16.h>

#define BATCH 64
#define CIN   16
#define H     256
#define W     256
#define HW    (H*W)
#define COUT  64
#define HO    254
#define WO    254

#define TS     16          // output tile edge
#define TIN    18          // staged input tile edge
#define CELL   24          // ushorts per (y,x) cell: 16 ci + 8 pad (48B stride, 16B-aligned)
#define NTY    8           // y-tiles per block (half strip)
#define NITEMS (4*TIN*TIN) // 1296 staging items per tile
#define IPT    6           // items per thread (5 full + 1 partial)

typedef short  bf16x8 __attribute__((ext_vector_type(8)));
typedef float  f32x16 __attribute__((ext_vector_type(16)));

static __device__ __forceinline__ unsigned short bfbits(float f) {
    __hip_bfloat16 h = __float2bfloat16(f);
    return *(unsigned short*)&h;
}

static __device__ __forceinline__ bf16x8 ld_frag(const ushort* p) {
    union { uint4 u; bf16x8 b; } cv;
    cv.u = *(const uint4*)p;
    return cv.b;
}

static __device__ __forceinline__ float fast_tanh(float x) {
    x = fminf(fmaxf(x, -15.f), 15.f);
    float e = __expf(2.f * x);
    return (e - 1.f) * __builtin_amdgcn_rcpf(e + 1.f);
}

// ---- repack: w[cout][ci][kh][kw] fp32 -> wpk[tap][cout][ci] bf16 (taps 0-8),
//      plus tap 9 = bias column: wpk[9][cout][ci] = (ci==0) ? bias[cout] : 0 ----
__global__ void repack_w(const float* __restrict__ w, const float* __restrict__ bias,
                         ushort* __restrict__ wpk) {
    int i = blockIdx.x * 256 + threadIdx.x;
    if (i < 9 * COUT * CIN) {
        int ci   = i & 15;
        int cout = (i >> 4) & 63;
        int tap  = i >> 10;
        wpk[i] = bfbits(w[(cout * CIN + ci) * 9 + tap]);
    } else if (i < 10 * COUT * CIN) {
        int j    = i - 9 * COUT * CIN;
        int ci   = j & 15;
        int cout = j >> 4;
        wpk[i] = (ci == 0) ? bfbits(bias[cout]) : (ushort)0;
    }
}

__global__ __launch_bounds__(256, 2)
void conv_min_tanh_strip(const float* __restrict__ x,
                         const ushort* __restrict__ wpk,
                         float* __restrict__ out) {
    __shared__ __align__(16) ushort xsm[2][TIN * TIN * CELL];  // 2 x 15552 B

    // bijective XCD swizzle (2048 % 8 == 0)
    const int bid = blockIdx.x;                 // 0..2047
    const int L   = (bid & 7) * 256 + (bid >> 3);
    const int b   = L >> 5;
    const int rr  = L & 31;
    const int yb0 = (rr >> 4) * (NTY * TS);     // 0 or 128
    const int x0  = (rr & 15) * TS;

    const int tid  = threadIdx.x;
    const int lane = tid & 63;
    const int wv   = tid >> 6;
    const int l31  = lane & 31;
    const int hi   = lane >> 5;   // k half: ci 0-7 vs 8-15

    const float* xp0 = x + (size_t)b * (CIN * HW);
    const float* xp1 = xp0 + HW;
    const float* xp2 = xp0 + 2 * HW;
    const float* xp3 = xp0 + 3 * HW;

    // ---- weights (9 taps) + bias tap, resident in VGPRs ----
    bf16x8 wf[10][2];
    #pragma unroll
    for (int tap = 0; tap < 10; ++tap)
        #pragma unroll
        for (int m = 0; m < 2; ++m)
            wf[tap][m] = ld_frag(wpk + tap * 1024 + (m * 32 + l31) * 16 + hi * 8);

    // ones B-frag for the bias tap: B[k=0][*] = 1.0 (k=0 lives in hi==0, elem 0)
    bf16x8 pone;
    #pragma unroll
    for (int j = 0; j < 8; ++j) pone[j] = 0;
    if (hi == 0) pone[0] = (short)0x3F80;

    // ---- staging address precompute (x-clamp REQUIRED: round-4 crash) ----
    int c0[IPT], dyv[IPT], lo[IPT];
    #pragma unroll
    for (int k = 0; k < IPT; ++k) {
        int it = tid + k * 256;
        int dx = it % TIN;
        int t2 = it / TIN;
        int dy = t2 % TIN;
        int cg = t2 / TIN;
        c0[k]  = cg * 4 * HW + min(x0 + dx, W - 1);
        dyv[k] = dy;
        lo[k]  = (dy * TIN + dx) * CELL + cg * 4;
    }

    // B-frag (pixel) cell bases: py = wv*4 + n*2 + (l31>>4), px = l31&15
    const int py_b = wv * 4 + (l31 >> 4);
    const int pxc  = l31 & 15;
    const int cb0  = ((py_b + 0) * TIN + pxc) * CELL + hi * 8;
    const int cb1  = ((py_b + 2) * TIN + pxc) * CELL + hi * 8;

    float fxA[IPT][4], fxB[IPT][4];

    auto stage_load = [&](int ybase, float (&fx)[IPT][4]) {
        #pragma unroll
        for (int k = 0; k < IPT; ++k) {
            if (k < 5 || tid < NITEMS - 5 * 256) {
                int gy  = min(ybase + dyv[k], H - 1);
                int idx = c0[k] + (gy << 8);
                fx[k][0] = xp0[idx];
                fx[k][1] = xp1[idx];
                fx[k][2] = xp2[idx];
                fx[k][3] = xp3[idx];
            }
        }
    };
    auto stage_write = [&](int buf, float (&fx)[IPT][4]) {
        #pragma unroll
        for (int k = 0; k < IPT; ++k) {
            if (k < 5 || tid < NITEMS - 5 * 256) {
                ushort4 v;
                v.x = bfbits(fx[k][0]);
                v.y = bfbits(fx[k][1]);
                v.z = bfbits(fx[k][2]);
                v.w = bfbits(fx[k][3]);
                *(ushort4*)&xsm[buf][lo[k]] = v;
            }
        }
    };

    // raw barrier: lgkmcnt(0) only — global prefetch loads stay in flight (T4)
    auto tile_barrier = [&]() {
        asm volatile("s_waitcnt lgkmcnt(0)" ::: "memory");
        __builtin_amdgcn_s_barrier();
        asm volatile("" ::: "memory");
    };

    // ---- prologue: tile 0 staged, tile 1 loads in flight ----
    stage_load(yb0, fxA);
    stage_write(0, fxA);
    stage_load(yb0 + TS, fxA);   // fxA regs free again (consumed by write)
    tile_barrier();

    auto tile_body = [&](int t, float (&fxw)[IPT][4], float (&fxl)[IPT][4]) {
        const int cur = t & 1;

        // issue loads for t+2 FIRST -> they ride out the whole iteration
        if (t + 2 < NTY) stage_load(yb0 + (t + 2) * TS, fxl);

        f32x16 acc[2][2];
        #pragma unroll
        for (int m = 0; m < 2; ++m)
            #pragma unroll
            for (int r = 0; r < 16; ++r) { acc[m][0][r] = 0.f; acc[m][1][r] = 0.f; }

        const ushort* xt = &xsm[cur][0];
        __builtin_amdgcn_s_setprio(1);
        #pragma unroll
        for (int tap = 0; tap < 9; ++tap) {
            const int kh = tap / 3, kw = tap - 3 * kh;
            const int toff = (kh * TIN + kw) * CELL;
            bf16x8 p0 = ld_frag(xt + cb0 + toff);
            bf16x8 p1 = ld_frag(xt + cb1 + toff);
            acc[0][0] = __builtin_amdgcn_mfma_f32_32x32x16_bf16(wf[tap][0], p0, acc[0][0], 0, 0, 0);
            acc[0][1] = __builtin_amdgcn_mfma_f32_32x32x16_bf16(wf[tap][0], p1, acc[0][1], 0, 0, 0);
            acc[1][0] = __builtin_amdgcn_mfma_f32_32x32x16_bf16(wf[tap][1], p0, acc[1][0], 0, 0, 0);
            acc[1][1] = __builtin_amdgcn_mfma_f32_32x32x16_bf16(wf[tap][1], p1, acc[1][1], 0, 0, 0);
        }
        // bias tap: D[cout][px] += bias[cout] * 1
        acc[0][0] = __builtin_amdgcn_mfma_f32_32x32x16_bf16(wf[9][0], pone, acc[0][0], 0, 0, 0);
        acc[0][1] = __builtin_amdgcn_mfma_f32_32x32x16_bf16(wf[9][0], pone, acc[0][1], 0, 0, 0);
        acc[1][0] = __builtin_amdgcn_mfma_f32_32x32x16_bf16(wf[9][1], pone, acc[1][0], 0, 0, 0);
        acc[1][1] = __builtin_amdgcn_mfma_f32_32x32x16_bf16(wf[9][1], pone, acc[1][1], 0, 0, 0);
        __builtin_amdgcn_s_setprio(0);

        // write next tile into the other buffer (counted vmcnt: t+2 loads stay out)
        if (t + 1 < NTY) stage_write(cur ^ 1, fxw);

        // epilogue: min over 64 couts (in-reg tree + one cross-half shfl)
        float res[2];
        #pragma unroll
        for (int n = 0; n < 2; ++n) {
            float v[16];
            #pragma unroll
            for (int r = 0; r < 16; ++r)
                v[r] = fminf(acc[0][n][r], acc[1][n][r]);
            #pragma unroll
            for (int s = 8; s >= 1; s >>= 1)
                #pragma unroll
                for (int r = 0; r < s; ++r)
                    v[r] = fminf(v[r], v[r + s]);
            res[n] = fminf(v[0], __shfl_xor(v[0], 32, 64));
        }
        float val = hi ? res[1] : res[0];
        int px_lin = wv * 64 + lane;
        int oy = yb0 + t * TS + (px_lin >> 4);
        int ox = x0 + (px_lin & 15);
        if (oy < HO && ox < WO)
            out[((size_t)b * HO + oy) * WO + ox] = fast_tanh(fast_tanh(val));

        tile_barrier();
    };

    #pragma unroll 1
    for (int t = 0; t < NTY; t += 2) {
        tile_body(t,     fxA, fxB);   // fxA holds t+1 data; load t+2 into fxB
        tile_body(t + 1, fxB, fxA);   // fxB holds t+2 data; load t+3 into fxA
    }
}

extern "C" void kernel_launch(void* const* d_in, const int* in_sizes, int n_in,
                              void* d_out, int out_size, void* d_ws, size_t ws_size,
                              hipStream_t stream) {
    const float* x    = (const float*)d_in[0];
    const float* w    = (const float*)d_in[1];
    const float* bias = (const float*)d_in[2];
    float* out        = (float*)d_out;
    ushort* wpk       = (ushort*)d_ws;   // 10*64*16 bf16 = 20480 B

    hipLaunchKernelGGL(repack_w, dim3(40), dim3(256), 0, stream, w, bias, wpk);
    hipLaunchKernelGGL(conv_min_tanh_strip, dim3(2048), dim3(256), 0, stream,
                       x, wpk, out);
}